// Round 6
// baseline (667.149 us; speedup 1.0000x reference)
//
#include <hip/hip_runtime.h>

#define NN 2048
#define KK 20
#define BB 16
#define TPRE 1.79989f   // relu(A) prefilter; key>=1.8 => v>=1.8-1e-4 (noise<1)
#define CAP 128         // candidate capacity per wave (mean ~74, 6.4 sigma)

typedef __attribute__((ext_vector_type(4))) float f32x4;

// ---------------------------------------------------------------------------
// Kernel 1: per-row exact top-K selection. One wave per row.
// v6 (unchanged this round, measured <164us): rank-based selection on packed
// u64 keys; slim EMIT (2 stores + 1 fire-and-forget colsum atomic).
//   packed = (float_bits(key) << 32) | (NN-1-idx)   (key>0 => bits monotonic)
//   rank(x) = #{y : packed_y > packed_x};  selected iff rank < K; slot = rank.
// Fallback only for cnt<K or cnt>CAP (P ~ 1e-10/row): full-row bisection +
// tie handling, re-reading global (row is L2/L3-hot).
// ---------------------------------------------------------------------------
__global__ __launch_bounds__(256) void topk_kernel(
    const float* __restrict__ A, const float* __restrict__ noise,
    int* __restrict__ sel_idx, float* __restrict__ sel_val,
    float* __restrict__ colsum)
{
    __shared__ unsigned long long cand_pk[4][CAP + 8];
    __shared__ float cand_val[4][CAP];
    __shared__ int   cand_idx[4][CAP];
    __shared__ int   tie_idx[4][64];
    __shared__ int   tie_cnt[4];

    const int lane = threadIdx.x & 63;
    const int wv   = threadIdx.x >> 6;
    const int row  = blockIdx.x * 4 + wv;          // 0 .. 32767
    const float* Ar = A     + (size_t)row * NN;
    const float* Nr = noise + (size_t)row * NN;
    const int colbase = row & ~(NN - 1);           // b * N
    const unsigned long long ltm = (1ull << lane) - 1ull;

    int*   si = sel_idx + (size_t)row * KK;
    float* sv = sel_val + (size_t)row * KK;

#define EMIT(POS, IDX, V)                                                      \
    do {                                                                       \
        int _p = (POS); int _i = (IDX); float _v = (V);                        \
        si[_p] = _i; sv[_p] = _v;                                              \
        atomicAdd(&colsum[colbase + _i], _v);                                  \
    } while (0)

    // ---- Load burst: 8 independent dwordx4 loads --------------------------
    float4 a[8];
#pragma unroll
    for (int c = 0; c < 8; ++c)
        a[c] = *(const float4*)(Ar + c * 256 + lane * 4);

    // ---- Phase 1: ballot-prefix compaction of v-candidates into LDS -------
    int cnt = 0;
#pragma unroll
    for (int c = 0; c < 8; ++c) {
        float av[4] = {a[c].x, a[c].y, a[c].z, a[c].w};
#pragma unroll
        for (int q = 0; q < 4; ++q) {
            float v = fmaxf(av[q], 0.f);
            bool p = v >= TPRE;
            unsigned long long m = __ballot(p);
            if (p) {
                int pos = cnt + __popcll(m & ltm);
                if (pos < CAP) {
                    cand_val[wv][pos] = v;
                    cand_idx[wv][pos] = c * 256 + lane * 4 + q;
                }
            }
            cnt += __popcll(m);
        }
    }

    bool done = false;
    if (cnt >= KK && cnt <= CAP) {
        // ---- Gather noise at candidate positions, pack sortable u64 -------
        int   i0 = (lane      < cnt) ? cand_idx[wv][lane]      : -1;
        int   i1 = (lane + 64 < cnt) ? cand_idx[wv][lane + 64] : -1;
        float v0 = (i0 >= 0) ? cand_val[wv][lane]      : 0.f;
        float v1 = (i1 >= 0) ? cand_val[wv][lane + 64] : 0.f;
        unsigned long long pk0 = ~0ull, pk1 = ~0ull;
        if (i0 >= 0) {
            float k0 = fmaf(Nr[i0], 1e-4f, v0);
            pk0 = ((unsigned long long)__float_as_uint(k0) << 32)
                | (unsigned)(NN - 1 - i0);
            cand_pk[wv][lane] = pk0;
        }
        if (i1 >= 0) {
            float k1 = fmaf(Nr[i1], 1e-4f, v1);
            pk1 = ((unsigned long long)__float_as_uint(k1) << 32)
                | (unsigned)(NN - 1 - i1);
            cand_pk[wv][lane + 64] = pk1;
        }
        // sentinel pad to multiple of 8 (0 < any real packed key)
        int nIter = (cnt + 7) & ~7;
        if (lane < nIter - cnt) cand_pk[wv][cnt + lane] = 0ull;

        // ---- Rank scan: unrolled x8, broadcast b64 reads, pipelined -------
        int r0 = 0, r1 = 0;
        for (int j = 0; j < nIter; j += 8) {
            unsigned long long b[8];
#pragma unroll
            for (int u = 0; u < 8; ++u) b[u] = cand_pk[wv][j + u];
#pragma unroll
            for (int u = 0; u < 8; ++u) {
                r0 += (b[u] > pk0);
                r1 += (b[u] > pk1);
            }
        }
        if (i0 >= 0 && r0 < KK) EMIT(r0, i0, v0);
        if (i1 >= 0 && r1 < KK) EMIT(r1, i1, v1);
        done = true;
    }

    if (!done) {
        // ---- Fallback (cold, exact): full-row re-read bisection -----------
        unsigned lo = 0u, hi = 0x7F800000u;
        unsigned tb = 0u;
        bool exact = false;
        while (hi - lo > 1u) {
            unsigned mid = (lo + hi) >> 1;
            float tm = __uint_as_float(mid);
            int c = 0;
            for (int j = 0; j < 32; ++j) {
                float av = Ar[j * 64 + lane];
                float nv = Nr[j * 64 + lane];
                float k = fmaf(nv, 1e-4f, fmaxf(av, 0.f));
                c += __popcll(__ballot(k >= tm));
            }
            if (c == KK) { tb = mid; exact = true; break; }
            if (c > KK) lo = mid; else hi = mid;
        }
        if (exact) {
            float t = __uint_as_float(tb);
            int run = 0;
            for (int j = 0; j < 32; ++j) {
                float av = Ar[j * 64 + lane];
                float nv = Nr[j * 64 + lane];
                float v = fmaxf(av, 0.f);
                float k = fmaf(nv, 1e-4f, v);
                bool p = k >= t;
                unsigned long long m = __ballot(p);
                if (p) EMIT(run + __popcll(m & ltm), j * 64 + lane, v);
                run += __popcll(m);
            }
        } else {
            // Exact tie at the K/K+1 boundary: strictly-greater first, then
            // ascending-index among ties (lax.top_k semantics).
            float t1 = __uint_as_float(lo);
            int run = 0;
            for (int j = 0; j < 32; ++j) {
                float av = Ar[j * 64 + lane];
                float nv = Nr[j * 64 + lane];
                float v = fmaxf(av, 0.f);
                float k = fmaf(nv, 1e-4f, v);
                bool p = k > t1;
                unsigned long long m = __ballot(p);
                if (p) EMIT(run + __popcll(m & ltm), j * 64 + lane, v);
                run += __popcll(m);
            }
            if (lane == 0) tie_cnt[wv] = 0;
            for (int j = 0; j < 32; ++j) {
                float av = Ar[j * 64 + lane];
                float nv = Nr[j * 64 + lane];
                float k = fmaf(nv, 1e-4f, fmaxf(av, 0.f));
                if (k == t1) {
                    int p = atomicAdd(&tie_cnt[wv], 1);
                    if (p < 64) tie_idx[wv][p] = j * 64 + lane;
                }
            }
            if (lane == 0) {
                int n = tie_cnt[wv]; if (n > 64) n = 64;
                int need = KK - run;
                for (int s = 0; s < need; ++s) {
                    int bq = 0, bidx = 0x7fffffff;
                    for (int q = 0; q < n; ++q) {
                        int v = tie_idx[wv][q];
                        if (v < bidx) { bidx = v; bq = q; }
                    }
                    tie_idx[wv][bq] = 0x7fffffff;
                    float v = fmaxf(Ar[bidx], 0.f);
                    EMIT(run + s, bidx, v);
                }
            }
        }
    }
#undef EMIT
}

// ---------------------------------------------------------------------------
// Kernel 2: dinv = (1 + 0.5*(rowsum + colsum))^-1/2.
// ---------------------------------------------------------------------------
__global__ __launch_bounds__(256) void dinv_kernel(
    const float* __restrict__ sel_val, const float* __restrict__ colsum,
    float* __restrict__ dinv)
{
    int r = blockIdx.x * 256 + threadIdx.x;        // 0 .. 32767
    const float* svp = sel_val + (size_t)r * KK;
    float rs = 0.f;
#pragma unroll
    for (int k = 0; k < KK; ++k) rs += svp[k];
    float d = 1.0f + 0.5f * (rs + colsum[r]);
    dinv[r] = 1.0f / sqrtf(d);                     // d >= 1 always
}

// ---------------------------------------------------------------------------
// Kernel 2b (v7): our own output zeroing. hipMemsetAsync(out, 256MB) showed
// up in rocprof as fillBufferAligned writing 1 GiB (4x amplification) at
// 165us/dispatch. A grid-stride float4 fill writes exactly 256 MiB and
// cannot be amplified. (If the 1 GiB fills persist in the profile, they are
// harness re-poison fills, not ours — decisive either way.)
// ---------------------------------------------------------------------------
__global__ __launch_bounds__(256) void zero_kernel(f32x4* __restrict__ out)
{
    const size_t total  = (size_t)BB * NN * (NN / 4);   // 16.78M float4
    const size_t stride = (size_t)gridDim.x * 256;
    f32x4 z = {0.f, 0.f, 0.f, 0.f};
    for (size_t i = (size_t)blockIdx.x * 256 + threadIdx.x; i < total; i += stride)
        out[i] = z;
}

// ---------------------------------------------------------------------------
// Kernel 3 (unchanged): global scatter onto zeroed output. One thread per
// (row,k) issues TWO fire-and-forget global atomicAdds:
//   out[r][j] += w  and  out[j][r] += w,  w = 0.5*v*d_r*d_j
// plus one thread per row for the diagonal d_r^2. Atomicity exactly handles
// mutual selection and self-loops.
// ---------------------------------------------------------------------------
__global__ __launch_bounds__(256) void scatter_kernel(
    const int* __restrict__ sel_idx, const float* __restrict__ sel_val,
    const float* __restrict__ dinv, float* __restrict__ out)
{
    int tid = blockIdx.x * 256 + threadIdx.x;      // 0 .. 32768*21-1
    int r = tid / 21;                              // magic-mul division
    int s = tid - r * 21;
    const int colbase = r & ~(NN - 1);
    const int i = r & (NN - 1);
    float dr = dinv[r];

    if (s == 20) {
        // (A+I) diagonal term
        atomicAdd(&out[(size_t)r * NN + i], dr * dr);
    } else {
        int   j = sel_idx[(size_t)r * KK + s];
        float v = sel_val[(size_t)r * KK + s];
        float w = 0.5f * v * dr * dinv[colbase + j];
        atomicAdd(&out[(size_t)r * NN + j], w);
        atomicAdd(&out[(size_t)(colbase + j) * NN + i], w);
    }
}

// ---------------------------------------------------------------------------
extern "C" void kernel_launch(void* const* d_in, const int* in_sizes, int n_in,
                              void* d_out, int out_size, void* d_ws, size_t ws_size,
                              hipStream_t stream)
{
    const float* A     = (const float*)d_in[0];
    const float* noise = (const float*)d_in[1];
    float* out = (float*)d_out;
    char*  ws  = (char*)d_ws;

    const int rows = BB * NN;                      // 32768
    // workspace layout (~5.5 MB total)
    size_t off = 0;
    int*   sel_idx = (int*)(ws + off);            off += (size_t)rows * KK * 4;   // 2.62 MB
    float* sel_val = (float*)(ws + off);          off += (size_t)rows * KK * 4;   // 2.62 MB
    float* colsum  = (float*)(ws + off);          off += (size_t)rows * 4;        // 128 KB
    float* dinv    = (float*)(ws + off);                                          // 128 KB

    hipMemsetAsync(colsum, 0, rows * sizeof(float), stream);

    zero_kernel<<<2048, 256, 0, stream>>>((f32x4*)out);
    topk_kernel<<<rows / 4, 256, 0, stream>>>(A, noise, sel_idx, sel_val, colsum);
    dinv_kernel<<<rows / 256, 256, 0, stream>>>(sel_val, colsum, dinv);
    scatter_kernel<<<rows * 21 / 256, 256, 0, stream>>>(sel_idx, sel_val, dinv, out);
}

// Round 7
// 658.277 us; speedup vs baseline: 1.0135x; 1.0135x over previous
//
#include <hip/hip_runtime.h>

#define NN 2048
#define KK 20
#define BB 16
#define TPRE 1.79989f   // relu(A) prefilter; key>=1.8 => v>=1.8-1e-4 (noise<1)
#define CAP 128         // candidate capacity per wave (mean ~74, 6.4 sigma)

typedef __attribute__((ext_vector_type(4))) float f32x4;

// ---------------------------------------------------------------------------
// Kernel 1 (v8): per-row exact top-K selection + FUSED output zeroing.
// topk is latency-bound (VALUBusy 24%, 1.5 TB/s read); the 256 MB output
// zero is pure write BW. Each block issues 8 NT float4 stores (its 32 KB
// slice of out) right AFTER its 8 A-row loads: loads are older in vmcnt
// order so compute never waits on the stores; they drain in the background
// across the block's lifetime. This deletes the standalone ~90us zero pass
// (and the driver's 4x-amplified memset before it).
// Selection (measured 166us): rank-based on packed u64 keys,
//   packed = (float_bits(key) << 32) | (NN-1-idx)   (key>0 => bits monotonic)
//   rank(x) = #{y : packed_y > packed_x};  selected iff rank < K; slot = rank.
// Fallback only for cnt<K or cnt>CAP (P ~ 1e-10/row): full-row bisection +
// tie handling, re-reading global (row is L2/L3-hot).
// ---------------------------------------------------------------------------
__global__ __launch_bounds__(256) void topk_kernel(
    const float* __restrict__ A, const float* __restrict__ noise,
    int* __restrict__ sel_idx, float* __restrict__ sel_val,
    float* __restrict__ colsum, float* __restrict__ out)
{
    __shared__ unsigned long long cand_pk[4][CAP + 8];
    __shared__ float cand_val[4][CAP];
    __shared__ int   cand_idx[4][CAP];
    __shared__ int   tie_idx[4][64];
    __shared__ int   tie_cnt[4];

    const int lane = threadIdx.x & 63;
    const int wv   = threadIdx.x >> 6;
    const int row  = blockIdx.x * 4 + wv;          // 0 .. 32767
    const float* Ar = A     + (size_t)row * NN;
    const float* Nr = noise + (size_t)row * NN;
    const int colbase = row & ~(NN - 1);           // b * N
    const unsigned long long ltm = (1ull << lane) - 1ull;

    int*   si = sel_idx + (size_t)row * KK;
    float* sv = sel_val + (size_t)row * KK;

#define EMIT(POS, IDX, V)                                                      \
    do {                                                                       \
        int _p = (POS); int _i = (IDX); float _v = (V);                        \
        si[_p] = _i; sv[_p] = _v;                                              \
        atomicAdd(&colsum[colbase + _i], _v);                                  \
    } while (0)

    // ---- Load burst: 8 independent dwordx4 loads (oldest in vmcnt) --------
    float4 a[8];
#pragma unroll
    for (int c = 0; c < 8; ++c)
        a[c] = *(const float4*)(Ar + c * 256 + lane * 4);

    // ---- Fused zero: 8 NT stores of this block's 32KB out-slice -----------
    // (issued after the loads; drains in background, never waited on)
    {
        f32x4* ob = (f32x4*)out + (size_t)blockIdx.x * 2048;
        f32x4 z = {0.f, 0.f, 0.f, 0.f};
#pragma unroll
        for (int k = 0; k < 8; ++k)
            __builtin_nontemporal_store(z, ob + k * 256 + threadIdx.x);
    }

    // ---- Phase 1: ballot-prefix compaction of v-candidates into LDS -------
    int cnt = 0;
#pragma unroll
    for (int c = 0; c < 8; ++c) {
        float av[4] = {a[c].x, a[c].y, a[c].z, a[c].w};
#pragma unroll
        for (int q = 0; q < 4; ++q) {
            float v = fmaxf(av[q], 0.f);
            bool p = v >= TPRE;
            unsigned long long m = __ballot(p);
            if (p) {
                int pos = cnt + __popcll(m & ltm);
                if (pos < CAP) {
                    cand_val[wv][pos] = v;
                    cand_idx[wv][pos] = c * 256 + lane * 4 + q;
                }
            }
            cnt += __popcll(m);
        }
    }

    bool done = false;
    if (cnt >= KK && cnt <= CAP) {
        // ---- Gather noise at candidate positions, pack sortable u64 -------
        int   i0 = (lane      < cnt) ? cand_idx[wv][lane]      : -1;
        int   i1 = (lane + 64 < cnt) ? cand_idx[wv][lane + 64] : -1;
        float v0 = (i0 >= 0) ? cand_val[wv][lane]      : 0.f;
        float v1 = (i1 >= 0) ? cand_val[wv][lane + 64] : 0.f;
        unsigned long long pk0 = ~0ull, pk1 = ~0ull;
        if (i0 >= 0) {
            float k0 = fmaf(Nr[i0], 1e-4f, v0);
            pk0 = ((unsigned long long)__float_as_uint(k0) << 32)
                | (unsigned)(NN - 1 - i0);
            cand_pk[wv][lane] = pk0;
        }
        if (i1 >= 0) {
            float k1 = fmaf(Nr[i1], 1e-4f, v1);
            pk1 = ((unsigned long long)__float_as_uint(k1) << 32)
                | (unsigned)(NN - 1 - i1);
            cand_pk[wv][lane + 64] = pk1;
        }
        // sentinel pad to multiple of 8 (0 < any real packed key)
        int nIter = (cnt + 7) & ~7;
        if (lane < nIter - cnt) cand_pk[wv][cnt + lane] = 0ull;

        // ---- Rank scan: unrolled x8, broadcast b64 reads, pipelined -------
        int r0 = 0, r1 = 0;
        for (int j = 0; j < nIter; j += 8) {
            unsigned long long b[8];
#pragma unroll
            for (int u = 0; u < 8; ++u) b[u] = cand_pk[wv][j + u];
#pragma unroll
            for (int u = 0; u < 8; ++u) {
                r0 += (b[u] > pk0);
                r1 += (b[u] > pk1);
            }
        }
        if (i0 >= 0 && r0 < KK) EMIT(r0, i0, v0);
        if (i1 >= 0 && r1 < KK) EMIT(r1, i1, v1);
        done = true;
    }

    if (!done) {
        // ---- Fallback (cold, exact): full-row re-read bisection -----------
        unsigned lo = 0u, hi = 0x7F800000u;
        unsigned tb = 0u;
        bool exact = false;
        while (hi - lo > 1u) {
            unsigned mid = (lo + hi) >> 1;
            float tm = __uint_as_float(mid);
            int c = 0;
            for (int j = 0; j < 32; ++j) {
                float av = Ar[j * 64 + lane];
                float nv = Nr[j * 64 + lane];
                float k = fmaf(nv, 1e-4f, fmaxf(av, 0.f));
                c += __popcll(__ballot(k >= tm));
            }
            if (c == KK) { tb = mid; exact = true; break; }
            if (c > KK) lo = mid; else hi = mid;
        }
        if (exact) {
            float t = __uint_as_float(tb);
            int run = 0;
            for (int j = 0; j < 32; ++j) {
                float av = Ar[j * 64 + lane];
                float nv = Nr[j * 64 + lane];
                float v = fmaxf(av, 0.f);
                float k = fmaf(nv, 1e-4f, v);
                bool p = k >= t;
                unsigned long long m = __ballot(p);
                if (p) EMIT(run + __popcll(m & ltm), j * 64 + lane, v);
                run += __popcll(m);
            }
        } else {
            // Exact tie at the K/K+1 boundary: strictly-greater first, then
            // ascending-index among ties (lax.top_k semantics).
            float t1 = __uint_as_float(lo);
            int run = 0;
            for (int j = 0; j < 32; ++j) {
                float av = Ar[j * 64 + lane];
                float nv = Nr[j * 64 + lane];
                float v = fmaxf(av, 0.f);
                float k = fmaf(nv, 1e-4f, v);
                bool p = k > t1;
                unsigned long long m = __ballot(p);
                if (p) EMIT(run + __popcll(m & ltm), j * 64 + lane, v);
                run += __popcll(m);
            }
            if (lane == 0) tie_cnt[wv] = 0;
            for (int j = 0; j < 32; ++j) {
                float av = Ar[j * 64 + lane];
                float nv = Nr[j * 64 + lane];
                float k = fmaf(nv, 1e-4f, fmaxf(av, 0.f));
                if (k == t1) {
                    int p = atomicAdd(&tie_cnt[wv], 1);
                    if (p < 64) tie_idx[wv][p] = j * 64 + lane;
                }
            }
            if (lane == 0) {
                int n = tie_cnt[wv]; if (n > 64) n = 64;
                int need = KK - run;
                for (int s = 0; s < need; ++s) {
                    int bq = 0, bidx = 0x7fffffff;
                    for (int q = 0; q < n; ++q) {
                        int v = tie_idx[wv][q];
                        if (v < bidx) { bidx = v; bq = q; }
                    }
                    tie_idx[wv][bq] = 0x7fffffff;
                    float v = fmaxf(Ar[bidx], 0.f);
                    EMIT(run + s, bidx, v);
                }
            }
        }
    }
#undef EMIT
}

// ---------------------------------------------------------------------------
// Kernel 2: dinv = (1 + 0.5*(rowsum + colsum))^-1/2.
// ---------------------------------------------------------------------------
__global__ __launch_bounds__(256) void dinv_kernel(
    const float* __restrict__ sel_val, const float* __restrict__ colsum,
    float* __restrict__ dinv)
{
    int r = blockIdx.x * 256 + threadIdx.x;        // 0 .. 32767
    const float* svp = sel_val + (size_t)r * KK;
    float rs = 0.f;
#pragma unroll
    for (int k = 0; k < KK; ++k) rs += svp[k];
    float d = 1.0f + 0.5f * (rs + colsum[r]);
    dinv[r] = 1.0f / sqrtf(d);                     // d >= 1 always
}

// ---------------------------------------------------------------------------
// Kernel 3 (unchanged): global scatter onto the (topk-zeroed) output. One
// thread per (row,k) issues TWO fire-and-forget global atomicAdds:
//   out[r][j] += w  and  out[j][r] += w,  w = 0.5*v*d_r*d_j
// plus one thread per row for the diagonal d_r^2. Atomicity exactly handles
// mutual selection and self-loops.
// ---------------------------------------------------------------------------
__global__ __launch_bounds__(256) void scatter_kernel(
    const int* __restrict__ sel_idx, const float* __restrict__ sel_val,
    const float* __restrict__ dinv, float* __restrict__ out)
{
    int tid = blockIdx.x * 256 + threadIdx.x;      // 0 .. 32768*21-1
    int r = tid / 21;                              // magic-mul division
    int s = tid - r * 21;
    const int colbase = r & ~(NN - 1);
    const int i = r & (NN - 1);
    float dr = dinv[r];

    if (s == 20) {
        // (A+I) diagonal term
        atomicAdd(&out[(size_t)r * NN + i], dr * dr);
    } else {
        int   j = sel_idx[(size_t)r * KK + s];
        float v = sel_val[(size_t)r * KK + s];
        float w = 0.5f * v * dr * dinv[colbase + j];
        atomicAdd(&out[(size_t)r * NN + j], w);
        atomicAdd(&out[(size_t)(colbase + j) * NN + i], w);
    }
}

// ---------------------------------------------------------------------------
extern "C" void kernel_launch(void* const* d_in, const int* in_sizes, int n_in,
                              void* d_out, int out_size, void* d_ws, size_t ws_size,
                              hipStream_t stream)
{
    const float* A     = (const float*)d_in[0];
    const float* noise = (const float*)d_in[1];
    float* out = (float*)d_out;
    char*  ws  = (char*)d_ws;

    const int rows = BB * NN;                      // 32768
    // workspace layout (~5.5 MB total)
    size_t off = 0;
    int*   sel_idx = (int*)(ws + off);            off += (size_t)rows * KK * 4;   // 2.62 MB
    float* sel_val = (float*)(ws + off);          off += (size_t)rows * KK * 4;   // 2.62 MB
    float* colsum  = (float*)(ws + off);          off += (size_t)rows * 4;        // 128 KB
    float* dinv    = (float*)(ws + off);                                          // 128 KB

    hipMemsetAsync(colsum, 0, rows * sizeof(float), stream);

    topk_kernel<<<rows / 4, 256, 0, stream>>>(A, noise, sel_idx, sel_val,
                                              colsum, out);
    dinv_kernel<<<rows / 256, 256, 0, stream>>>(sel_val, colsum, dinv);
    scatter_kernel<<<rows * 21 / 256, 256, 0, stream>>>(sel_idx, sel_val, dinv, out);
}

// Round 8
// 638.029 us; speedup vs baseline: 1.0456x; 1.0317x over previous
//
#include <hip/hip_runtime.h>

#define NN 2048
#define KK 20
#define BB 16
#define TPRE 1.79989f   // relu(A) prefilter; key>=1.8 => v>=1.8-1e-4 (noise<1)
#define CAP 128         // candidate capacity per wave (mean ~74, 6.4 sigma)
#define CSLOT 64        // incoming-list capacity per column (Poisson(20): P(>64)~6e-14)
#define DR 8            // rows per block in out_row_kernel (divides 2048)

typedef __attribute__((ext_vector_type(4))) float f32x4;

// ---------------------------------------------------------------------------
// Kernel 1: per-row exact top-K selection. One wave per row.
// Exactly the round-4 v5 version (measured 167-171us): rank-based selection
// on packed u64 keys + full EMIT (sel, colsum, col_cnt/col_src incoming
// lists — needed again because the output stage is a per-row gather).
//   packed = (float_bits(key) << 32) | (NN-1-idx)   (key>0 => bits monotonic)
//   rank(x) = #{y : packed_y > packed_x};  selected iff rank < K; slot = rank.
// Fallback only for cnt<K or cnt>CAP (P ~ 1e-10/row): full-row bisection +
// tie handling, re-reading global (row is L2/L3-hot).
// ---------------------------------------------------------------------------
__global__ __launch_bounds__(256) void topk_kernel(
    const float* __restrict__ A, const float* __restrict__ noise,
    int* __restrict__ sel_idx, float* __restrict__ sel_val,
    float* __restrict__ colsum, int* __restrict__ col_cnt,
    unsigned short* __restrict__ col_src)
{
    __shared__ unsigned long long cand_pk[4][CAP + 8];
    __shared__ float cand_val[4][CAP];
    __shared__ int   cand_idx[4][CAP];
    __shared__ int   tie_idx[4][64];
    __shared__ int   tie_cnt[4];

    const int lane = threadIdx.x & 63;
    const int wv   = threadIdx.x >> 6;
    const int row  = blockIdx.x * 4 + wv;          // 0 .. 32767
    const float* Ar = A     + (size_t)row * NN;
    const float* Nr = noise + (size_t)row * NN;
    const int colbase = row & ~(NN - 1);           // b * N
    const unsigned long long ltm = (1ull << lane) - 1ull;

    int*   si = sel_idx + (size_t)row * KK;
    float* sv = sel_val + (size_t)row * KK;

#define EMIT(POS, IDX, V)                                                      \
    do {                                                                       \
        int _p = (POS); int _i = (IDX); float _v = (V);                        \
        si[_p] = _i; sv[_p] = _v;                                              \
        atomicAdd(&colsum[colbase + _i], _v);                                  \
        int _s = atomicAdd(&col_cnt[colbase + _i], 1);                         \
        if (_s < CSLOT)                                                        \
            col_src[(size_t)(colbase + _i) * CSLOT + _s] =                     \
                (unsigned short)(((row & (NN - 1)) << 5) | _p);                \
    } while (0)

    // ---- Load burst: 8 independent dwordx4 loads --------------------------
    float4 a[8];
#pragma unroll
    for (int c = 0; c < 8; ++c)
        a[c] = *(const float4*)(Ar + c * 256 + lane * 4);

    // ---- Phase 1: ballot-prefix compaction of v-candidates into LDS -------
    int cnt = 0;
#pragma unroll
    for (int c = 0; c < 8; ++c) {
        float av[4] = {a[c].x, a[c].y, a[c].z, a[c].w};
#pragma unroll
        for (int q = 0; q < 4; ++q) {
            float v = fmaxf(av[q], 0.f);
            bool p = v >= TPRE;
            unsigned long long m = __ballot(p);
            if (p) {
                int pos = cnt + __popcll(m & ltm);
                if (pos < CAP) {
                    cand_val[wv][pos] = v;
                    cand_idx[wv][pos] = c * 256 + lane * 4 + q;
                }
            }
            cnt += __popcll(m);
        }
    }

    bool done = false;
    if (cnt >= KK && cnt <= CAP) {
        // ---- Gather noise at candidate positions, pack sortable u64 -------
        int   i0 = (lane      < cnt) ? cand_idx[wv][lane]      : -1;
        int   i1 = (lane + 64 < cnt) ? cand_idx[wv][lane + 64] : -1;
        float v0 = (i0 >= 0) ? cand_val[wv][lane]      : 0.f;
        float v1 = (i1 >= 0) ? cand_val[wv][lane + 64] : 0.f;
        unsigned long long pk0 = ~0ull, pk1 = ~0ull;
        if (i0 >= 0) {
            float k0 = fmaf(Nr[i0], 1e-4f, v0);
            pk0 = ((unsigned long long)__float_as_uint(k0) << 32)
                | (unsigned)(NN - 1 - i0);
            cand_pk[wv][lane] = pk0;
        }
        if (i1 >= 0) {
            float k1 = fmaf(Nr[i1], 1e-4f, v1);
            pk1 = ((unsigned long long)__float_as_uint(k1) << 32)
                | (unsigned)(NN - 1 - i1);
            cand_pk[wv][lane + 64] = pk1;
        }
        // sentinel pad to multiple of 8 (0 < any real packed key)
        int nIter = (cnt + 7) & ~7;
        if (lane < nIter - cnt) cand_pk[wv][cnt + lane] = 0ull;

        // ---- Rank scan: unrolled x8, broadcast b64 reads, pipelined -------
        int r0 = 0, r1 = 0;
        for (int j = 0; j < nIter; j += 8) {
            unsigned long long b[8];
#pragma unroll
            for (int u = 0; u < 8; ++u) b[u] = cand_pk[wv][j + u];
#pragma unroll
            for (int u = 0; u < 8; ++u) {
                r0 += (b[u] > pk0);
                r1 += (b[u] > pk1);
            }
        }
        if (i0 >= 0 && r0 < KK) EMIT(r0, i0, v0);
        if (i1 >= 0 && r1 < KK) EMIT(r1, i1, v1);
        done = true;
    }

    if (!done) {
        // ---- Fallback (cold, exact): full-row re-read bisection -----------
        unsigned lo = 0u, hi = 0x7F800000u;
        unsigned tb = 0u;
        bool exact = false;
        while (hi - lo > 1u) {
            unsigned mid = (lo + hi) >> 1;
            float tm = __uint_as_float(mid);
            int c = 0;
            for (int j = 0; j < 32; ++j) {
                float av = Ar[j * 64 + lane];
                float nv = Nr[j * 64 + lane];
                float k = fmaf(nv, 1e-4f, fmaxf(av, 0.f));
                c += __popcll(__ballot(k >= tm));
            }
            if (c == KK) { tb = mid; exact = true; break; }
            if (c > KK) lo = mid; else hi = mid;
        }
        if (exact) {
            float t = __uint_as_float(tb);
            int run = 0;
            for (int j = 0; j < 32; ++j) {
                float av = Ar[j * 64 + lane];
                float nv = Nr[j * 64 + lane];
                float v = fmaxf(av, 0.f);
                float k = fmaf(nv, 1e-4f, v);
                bool p = k >= t;
                unsigned long long m = __ballot(p);
                if (p) EMIT(run + __popcll(m & ltm), j * 64 + lane, v);
                run += __popcll(m);
            }
        } else {
            // Exact tie at the K/K+1 boundary: strictly-greater first, then
            // ascending-index among ties (lax.top_k semantics).
            float t1 = __uint_as_float(lo);
            int run = 0;
            for (int j = 0; j < 32; ++j) {
                float av = Ar[j * 64 + lane];
                float nv = Nr[j * 64 + lane];
                float v = fmaxf(av, 0.f);
                float k = fmaf(nv, 1e-4f, v);
                bool p = k > t1;
                unsigned long long m = __ballot(p);
                if (p) EMIT(run + __popcll(m & ltm), j * 64 + lane, v);
                run += __popcll(m);
            }
            if (lane == 0) tie_cnt[wv] = 0;
            for (int j = 0; j < 32; ++j) {
                float av = Ar[j * 64 + lane];
                float nv = Nr[j * 64 + lane];
                float k = fmaf(nv, 1e-4f, fmaxf(av, 0.f));
                if (k == t1) {
                    int p = atomicAdd(&tie_cnt[wv], 1);
                    if (p < 64) tie_idx[wv][p] = j * 64 + lane;
                }
            }
            if (lane == 0) {
                int n = tie_cnt[wv]; if (n > 64) n = 64;
                int need = KK - run;
                for (int s = 0; s < need; ++s) {
                    int bq = 0, bidx = 0x7fffffff;
                    for (int q = 0; q < n; ++q) {
                        int v = tie_idx[wv][q];
                        if (v < bidx) { bidx = v; bq = q; }
                    }
                    tie_idx[wv][bq] = 0x7fffffff;
                    float v = fmaxf(Ar[bidx], 0.f);
                    EMIT(run + s, bidx, v);
                }
            }
        }
    }
#undef EMIT
}

// ---------------------------------------------------------------------------
// Kernel 2: dinv = (1 + 0.5*(rowsum + colsum))^-1/2.
// ---------------------------------------------------------------------------
__global__ __launch_bounds__(256) void dinv_kernel(
    const float* __restrict__ sel_val, const float* __restrict__ colsum,
    float* __restrict__ dinv)
{
    int r = blockIdx.x * 256 + threadIdx.x;        // 0 .. 32767
    const float* svp = sel_val + (size_t)r * KK;
    float rs = 0.f;
#pragma unroll
    for (int k = 0; k < KK; ++k) rs += svp[k];
    float d = 1.0f + 0.5f * (rs + colsum[r]);
    dinv[r] = 1.0f / sqrtf(d);                     // d >= 1 always
}

// ---------------------------------------------------------------------------
// Kernel 3 (v9): pipelined per-row gather — writes each output row EXACTLY
// once (no zero pass, no global atomics). 4096 blocks x DR=8 rows. Per row:
// zero 8KB LDS -> barrier -> LDS atomics (diag + outgoing + incoming) ->
// barrier -> stream 8KB out. The scattered operands are prefetched into a
// statically-indexed double-buffer: A-stage (col_cnt/col_src/sel outgoing/
// dinv[r]) two rows ahead, B-stage (the loads depending on A: incoming
// sel_val, dinv[j]) one row ahead — their latency hides under the previous
// row's stream+barriers. All B operands are L2-resident (dinv 128KB,
// sel_val 2.6MB). Same-thread LDS RAW (stream then re-zero same addresses)
// is in-order; cross-thread hazards covered by the two barriers.
// ---------------------------------------------------------------------------
__global__ __launch_bounds__(256) void out_row_kernel(
    const int* __restrict__ sel_idx, const float* __restrict__ sel_val,
    const int* __restrict__ col_cnt, const unsigned short* __restrict__ col_src,
    const float* __restrict__ dinv, float* __restrict__ out)
{
    __shared__ float rowbuf[NN];
    const int t = threadIdx.x;
    const int r0 = blockIdx.x * DR;
    const int colbase = r0 & ~(NN - 1);            // DR divides NN: constant

    int   cntA[2]; int joA[2]; float voA[2]; float drA[2];
    unsigned short pkA[2];
    float viB[2], djiB[2], djoB[2]; int srowB[2];

#define LOAD_A(slot, rr)                                                     \
    do {                                                                     \
        int _r = (rr);                                                       \
        cntA[slot] = col_cnt[_r];                                            \
        drA[slot]  = dinv[_r];                                               \
        if (t < CSLOT) pkA[slot] = col_src[(size_t)_r * CSLOT + t];          \
        if (t < KK) { joA[slot] = sel_idx[(size_t)_r * KK + t];              \
                      voA[slot] = sel_val[(size_t)_r * KK + t]; }            \
    } while (0)

#define LOAD_B(slot)                                                         \
    do {                                                                     \
        if (t < KK) djoB[slot] = dinv[colbase + joA[slot]];                  \
        if (t < CSLOT) {                                                     \
            int _sr = pkA[slot] >> 5, _k = pkA[slot] & 31;                   \
            srowB[slot] = _sr;                                               \
            viB[slot]  = sel_val[(size_t)(colbase + _sr) * KK + _k];         \
            djiB[slot] = dinv[colbase + _sr];                                \
        }                                                                    \
    } while (0)

    LOAD_A(0, r0);
    LOAD_A(1, r0 + 1);
    LOAD_B(0);

#pragma unroll
    for (int it = 0; it < DR; ++it) {
        const int r = r0 + it;
        const int cur = it & 1, nxt = cur ^ 1;

        // zero this row's LDS buffer (same addresses this thread streamed
        // last iteration -> same-thread in-order, no extra barrier needed)
        f32x4 z = {0.f, 0.f, 0.f, 0.f};
        *(f32x4*)(rowbuf + t * 4) = z;
        *(f32x4*)(rowbuf + 1024 + t * 4) = z;
        __syncthreads();

        // accumulate from prefetched registers
        float dr = drA[cur];
        if (t == 0) atomicAdd(&rowbuf[r & (NN - 1)], dr * dr);
        if (t < KK)
            atomicAdd(&rowbuf[joA[cur]], 0.5f * voA[cur] * dr * djoB[cur]);
        int cnt = cntA[cur]; if (cnt > CSLOT) cnt = CSLOT;
        if (t < cnt)
            atomicAdd(&rowbuf[srowB[cur]], 0.5f * viB[cur] * dr * djiB[cur]);

        // prefetch: A two rows ahead (into the slot just consumed),
        // B one row ahead (consumes A(nxt) issued last iteration)
        if (it + 2 < DR) LOAD_A(cur, r + 2);
        if (it + 1 < DR) LOAD_B(nxt);
        __syncthreads();

        // stream the finished row out (write-once, coalesced)
        size_t bb = (size_t)r * NN;
        *(f32x4*)(out + bb + t * 4)        = *(const f32x4*)(rowbuf + t * 4);
        *(f32x4*)(out + bb + 1024 + t * 4) = *(const f32x4*)(rowbuf + 1024 + t * 4);
    }
#undef LOAD_A
#undef LOAD_B
}

// ---------------------------------------------------------------------------
extern "C" void kernel_launch(void* const* d_in, const int* in_sizes, int n_in,
                              void* d_out, int out_size, void* d_ws, size_t ws_size,
                              hipStream_t stream)
{
    const float* A     = (const float*)d_in[0];
    const float* noise = (const float*)d_in[1];
    float* out = (float*)d_out;
    char*  ws  = (char*)d_ws;

    const int rows = BB * NN;                      // 32768
    // workspace layout (~9.6 MB total — round-0 proven size)
    size_t off = 0;
    int*   sel_idx = (int*)(ws + off);            off += (size_t)rows * KK * 4;   // 2.62 MB
    float* sel_val = (float*)(ws + off);          off += (size_t)rows * KK * 4;   // 2.62 MB
    float* colsum  = (float*)(ws + off);          off += (size_t)rows * 4;        // 128 KB
    float* dinv    = (float*)(ws + off);          off += (size_t)rows * 4;        // 128 KB
    int*   col_cnt = (int*)(ws + off);            off += (size_t)rows * 4;        // 128 KB
    unsigned short* col_src = (unsigned short*)(ws + off);                        // 4 MB

    hipMemsetAsync(colsum, 0, rows * sizeof(float), stream);
    hipMemsetAsync(col_cnt, 0, rows * sizeof(int), stream);

    topk_kernel<<<rows / 4, 256, 0, stream>>>(A, noise, sel_idx, sel_val,
                                              colsum, col_cnt, col_src);
    dinv_kernel<<<rows / 256, 256, 0, stream>>>(sel_val, colsum, dinv);
    out_row_kernel<<<rows / DR, 256, 0, stream>>>(sel_idx, sel_val, col_cnt,
                                                  col_src, dinv, out);
}